// Round 10
// baseline (292.437 us; speedup 1.0000x reference)
//
#include <hip/hip_runtime.h>
#include <hip/hip_bf16.h>
#include <hip/hip_fp16.h>

#define NN 50000
#define NE 800000
#define CAP 64   // bucket capacity/node. deg ~ Poisson(16): P(deg>63) ~ 1e-19.
#define LDB 136  // LDS row stride (f16) for B tiles: 272B, 16B-aligned, 2-way bank max

using f16x8 = __attribute__((ext_vector_type(8))) _Float16;
using f32x4 = __attribute__((ext_vector_type(4))) float;

__device__ inline f16x8 cvt8(const float4 f0, const float4 f1) {
  f16x8 r;
  r[0] = (_Float16)f0.x; r[1] = (_Float16)f0.y;
  r[2] = (_Float16)f0.z; r[3] = (_Float16)f0.w;
  r[4] = (_Float16)f1.x; r[5] = (_Float16)f1.y;
  r[6] = (_Float16)f1.z; r[7] = (_Float16)f1.w;
  return r;
}

// fma 8 f16 lanes of r (as 4x half2) into acc[8] with weight w
__device__ inline void fma8(float* acc, const uint4 r, const float w) {
  const __half2* hp = (const __half2*)&r;
#pragma unroll
  for (int q = 0; q < 4; ++q) {
    const float2 f = __half22float2(hp[q]);
    acc[2 * q]     += w * f.x;
    acc[2 * q + 1] += w * f.y;
  }
}

// ---------------- Weight convert+transpose: W1[128][256]->W1t[256][128] f16,
// W2[256][32]->W2t[32][256] f16. Tiny (40K elems), runs once. -----------------
__global__ __launch_bounds__(256) void k_cvt(const float* __restrict__ W1,
                                             const float* __restrict__ W2,
                                             __half* __restrict__ W1t,
                                             __half* __restrict__ W2t) {
  const int idx = blockIdx.x * 256 + threadIdx.x;
  if (idx < 128 * 256) {
    const int k = idx >> 8, n = idx & 255;
    W1t[n * 128 + k] = __float2half(W1[idx]);
  } else {
    const int i2 = idx - 128 * 256;           // < 8192
    const int k = i2 >> 5, n = i2 & 31;
    W2t[n * 256 + k] = __float2half(W2[i2]);
  }
}

// ---------------- Layer-1 GEMM via MFMA 16x16x32 f16 -------------------------
// Block: 256 thr = 4 waves, 128 rows x 128 cols (grid 391 x 2; col-half = head
// pair). B (W1t) staged in LDS; A fragments loaded from global x + cvt f32->f16.
// SWAPPED operands: mfma(B,A,acc) => lane holds row = lane&15,
// cols = ct*16 + (lane>>4)*4 + reg  -> 8B packed stores, cheap logit reduce.
__global__ __launch_bounds__(256) void k_gemm1m(
    const float* __restrict__ x, const __half* __restrict__ W1t,
    const float* __restrict__ a_src, const float* __restrict__ a_dst,
    __half* __restrict__ xl1h, float* __restrict__ ls1, float* __restrict__ ld1) {
  __shared__ _Float16 Bs[128 * LDB];
  const int t = threadIdx.x;
  const int row0 = blockIdx.x * 128;
  const int colb = blockIdx.y * 128;
  // stage B: 128 cols x 128 k f16 = 2048 uint4
#pragma unroll
  for (int it = 0; it < 8; ++it) {
    const int idx = t + it * 256;
    const int n = idx >> 4, kk = (idx & 15) * 8;
    const uint4 v = *(const uint4*)&W1t[(size_t)(colb + n) * 128 + kk];
    *(uint4*)&Bs[n * LDB + kk] = v;
  }
  const int wid = t >> 6, lane = t & 63;
  const int l15 = lane & 15, lg4 = lane >> 4;
  // A fragments: 2 row-tiles x 4 k-steps, direct from global x (f32->f16)
  f16x8 a[2][4];
#pragma unroll
  for (int rt = 0; rt < 2; ++rt) {
    int arow = row0 + wid * 32 + rt * 16 + l15;
    arow = arow < NN ? arow : NN - 1;
    const float* xr = x + (size_t)arow * 128;
#pragma unroll
    for (int ks = 0; ks < 4; ++ks)
      a[rt][ks] = cvt8(*(const float4*)&xr[ks * 32 + lg4 * 8],
                       *(const float4*)&xr[ks * 32 + lg4 * 8 + 4]);
  }
  __syncthreads();
  f32x4 acc[2][8];
#pragma unroll
  for (int rt = 0; rt < 2; ++rt)
#pragma unroll
    for (int ct = 0; ct < 8; ++ct) acc[rt][ct] = (f32x4){0.f, 0.f, 0.f, 0.f};
#pragma unroll
  for (int ct = 0; ct < 8; ++ct) {
#pragma unroll
    for (int ks = 0; ks < 4; ++ks) {
      const f16x8 b = *(const f16x8*)&Bs[(ct * 16 + l15) * LDB + ks * 32 + lg4 * 8];
      acc[0][ct] = __builtin_amdgcn_mfma_f32_16x16x32_f16(b, a[0][ks], acc[0][ct], 0, 0, 0);
      acc[1][ct] = __builtin_amdgcn_mfma_f32_16x16x32_f16(b, a[1][ks], acc[1][ct], 0, 0, 0);
    }
  }
  // epilogue: lane owns rows (row0+wid*32+rt*16+l15), cols ct*16+lg4*4+reg
  float pss[2][2] = {{0.f, 0.f}, {0.f, 0.f}};
  float psd[2][2] = {{0.f, 0.f}, {0.f, 0.f}};
#pragma unroll
  for (int ct = 0; ct < 8; ++ct) {
    const int c0 = colb + ct * 16 + lg4 * 4;
    const float4 as4 = *(const float4*)&a_src[c0];
    const float4 ad4 = *(const float4*)&a_dst[c0];
    const int hl = ct >> 2;
#pragma unroll
    for (int rt = 0; rt < 2; ++rt) {
      const int row = row0 + wid * 32 + rt * 16 + l15;
      const __half2 p0 = __floats2half2_rn(acc[rt][ct][0], acc[rt][ct][1]);
      const __half2 p1 = __floats2half2_rn(acc[rt][ct][2], acc[rt][ct][3]);
      uint2 pv;
      pv.x = *(const unsigned*)&p0;
      pv.y = *(const unsigned*)&p1;
      if (row < NN) *(uint2*)&xl1h[(size_t)row * 256 + c0] = pv;
      pss[rt][hl] += acc[rt][ct][0] * as4.x + acc[rt][ct][1] * as4.y +
                     acc[rt][ct][2] * as4.z + acc[rt][ct][3] * as4.w;
      psd[rt][hl] += acc[rt][ct][0] * ad4.x + acc[rt][ct][1] * ad4.y +
                     acc[rt][ct][2] * ad4.z + acc[rt][ct][3] * ad4.w;
    }
  }
#pragma unroll
  for (int rt = 0; rt < 2; ++rt)
#pragma unroll
    for (int hl = 0; hl < 2; ++hl) {
      float s = pss[rt][hl], d = psd[rt][hl];
      s += __shfl_xor(s, 16); s += __shfl_xor(s, 32);
      d += __shfl_xor(d, 16); d += __shfl_xor(d, 32);
      const int row = row0 + wid * 32 + rt * 16 + l15;
      if (lg4 == 0 && row < NN) {
        const int h = blockIdx.y * 2 + hl;
        ls1[row * 4 + h] = s;
        ld1[row * 4 + h] = d;
      }
    }
}

// ---------------- Bucket CSR build (no scan, no hist) ------------------------
// Nontemporal scatter-writes: don't pollute L2 ahead of gather1's streaming.
__global__ void k_scatter(const int* __restrict__ ei, int* __restrict__ cursor,
                          int* __restrict__ edge_src) {
  const int e = blockIdx.x * 256 + threadIdx.x;
  const int s = ei[e], d = ei[NE + e];
  const int pos = atomicAdd(&cursor[d], 1);
  if (pos < CAP) __builtin_nontemporal_store(s, &edge_src[(d << 6) + pos]);
}

// ---------------- Layer-1 gather: 2 nodes/wave, 32 lanes x 16B ---------------
// Row = 256 f16 = 512B = 32 lanes x uint4. Lane ln covers f16 channels
// 8ln..8ln+7, head h = ln>>3. 4-way edge unroll x 2 nodes/wave = 8 independent
// 512B row fetches in flight per wave. Edge indices load as one int4 (bucket
// base is 64-aligned). Softmax shift-invariance: no segment_max needed.
__global__ __launch_bounds__(256) void k_gather1(
    const uint4* __restrict__ xl1q, const float* __restrict__ ls1,
    const float* __restrict__ ld1, const int* __restrict__ cnt,
    const int* __restrict__ edge_src, const float* __restrict__ b1,
    uint4* __restrict__ h1q) {
  const int lane = threadIdx.x & 63;
  const int ln = lane & 31;
  const int n = blockIdx.x * 8 + ((threadIdx.x >> 6) << 1) + (lane >> 5);
  const int h = ln >> 3;
  const float ldn = ld1[n * 4 + h];
  float lg = ls1[n * 4 + h] + ldn;            // self loop
  lg = lg > 0.f ? lg : 0.2f * lg;
  const float w = __expf(lg);
  float acc[8];
  {
    const uint4 v = xl1q[(size_t)n * 32 + ln];
    const __half2* hp = (const __half2*)&v;
#pragma unroll
    for (int q = 0; q < 4; ++q) {
      const float2 f = __half22float2(hp[q]);
      acc[2 * q]     = w * f.x;
      acc[2 * q + 1] = w * f.y;
    }
  }
  float wsum = w;
  const int beg = n << 6;
  const int m = min(cnt[n], CAP);
  int i = 0;
  for (; i + 4 <= m; i += 4) {
    const int4 ss = *(const int4*)&edge_src[beg + i];
    const uint4 r0 = xl1q[(size_t)ss.x * 32 + ln];
    const uint4 r1 = xl1q[(size_t)ss.y * 32 + ln];
    const uint4 r2 = xl1q[(size_t)ss.z * 32 + ln];
    const uint4 r3 = xl1q[(size_t)ss.w * 32 + ln];
    float l0 = ls1[ss.x * 4 + h] + ldn;
    float l1 = ls1[ss.y * 4 + h] + ldn;
    float l2 = ls1[ss.z * 4 + h] + ldn;
    float l3 = ls1[ss.w * 4 + h] + ldn;
    l0 = l0 > 0.f ? l0 : 0.2f * l0;
    l1 = l1 > 0.f ? l1 : 0.2f * l1;
    l2 = l2 > 0.f ? l2 : 0.2f * l2;
    l3 = l3 > 0.f ? l3 : 0.2f * l3;
    const float w0 = __expf(l0), w1 = __expf(l1);
    const float w2 = __expf(l2), w3 = __expf(l3);
    wsum += (w0 + w1) + (w2 + w3);
    fma8(acc, r0, w0);
    fma8(acc, r1, w1);
    fma8(acc, r2, w2);
    fma8(acc, r3, w3);
  }
  for (; i < m; ++i) {
    const int s0 = edge_src[beg + i];
    const uint4 r0 = xl1q[(size_t)s0 * 32 + ln];
    float l0 = ls1[s0 * 4 + h] + ldn;
    l0 = l0 > 0.f ? l0 : 0.2f * l0;
    const float w0 = __expf(l0);
    wsum += w0;
    fma8(acc, r0, w0);
  }
  const float inv = 1.f / wsum;
  const float4 bb0 = *(const float4*)&b1[ln * 8];
  const float4 bb1 = *(const float4*)&b1[ln * 8 + 4];
  const float bb[8] = {bb0.x, bb0.y, bb0.z, bb0.w, bb1.x, bb1.y, bb1.z, bb1.w};
  uint4 o;
  __half2* op = (__half2*)&o;
#pragma unroll
  for (int q = 0; q < 4; ++q)
    op[q] = __floats2half2_rn(fmaxf(acc[2 * q] * inv + bb[2 * q], 0.f),
                              fmaxf(acc[2 * q + 1] * inv + bb[2 * q + 1], 0.f));
  h1q[(size_t)n * 32 + ln] = o;
}

// ---------------- Layer-2 GEMM via MFMA 16x16x32 f16 (LDS-free) --------------
// Block: 256 thr = 4 waves x 16 rows; N=32 (2 col-tiles), K=256 (8 k-steps).
// W2t frags register-resident (8 KB, L2-hot). Swapped operands as in gemm1m.
__global__ __launch_bounds__(256) void k_gemm2m(
    const __half* __restrict__ h1h, const __half* __restrict__ W2t,
    const float* __restrict__ a_src2, const float* __restrict__ a_dst2,
    __half* __restrict__ xl2h, float* __restrict__ ls2, float* __restrict__ ld2) {
  const int t = threadIdx.x;
  const int wid = t >> 6, lane = t & 63;
  const int l15 = lane & 15, lg4 = lane >> 4;
  const int row0 = blockIdx.x * 64;
  int arow = row0 + wid * 16 + l15;
  const bool ok = arow < NN;
  arow = ok ? arow : NN - 1;
  f16x8 bfr[2][8];
#pragma unroll
  for (int ct = 0; ct < 2; ++ct)
#pragma unroll
    for (int ks = 0; ks < 8; ++ks)
      bfr[ct][ks] = *(const f16x8*)&W2t[(size_t)(ct * 16 + l15) * 256 + ks * 32 + lg4 * 8];
  f16x8 a[8];
  const __half* hr = h1h + (size_t)arow * 256;
#pragma unroll
  for (int ks = 0; ks < 8; ++ks)
    a[ks] = *(const f16x8*)&hr[ks * 32 + lg4 * 8];
  f32x4 acc[2] = {(f32x4){0.f, 0.f, 0.f, 0.f}, (f32x4){0.f, 0.f, 0.f, 0.f}};
#pragma unroll
  for (int ks = 0; ks < 8; ++ks) {
    acc[0] = __builtin_amdgcn_mfma_f32_16x16x32_f16(bfr[0][ks], a[ks], acc[0], 0, 0, 0);
    acc[1] = __builtin_amdgcn_mfma_f32_16x16x32_f16(bfr[1][ks], a[ks], acc[1], 0, 0, 0);
  }
  // lane owns row arow, cols ct*16 + lg4*4 + reg
  float ps = 0.f, pd = 0.f;
#pragma unroll
  for (int ct = 0; ct < 2; ++ct) {
    const int c0 = ct * 16 + lg4 * 4;
    const float4 as4 = *(const float4*)&a_src2[c0];
    const float4 ad4 = *(const float4*)&a_dst2[c0];
    const __half2 p0 = __floats2half2_rn(acc[ct][0], acc[ct][1]);
    const __half2 p1 = __floats2half2_rn(acc[ct][2], acc[ct][3]);
    uint2 pv;
    pv.x = *(const unsigned*)&p0;
    pv.y = *(const unsigned*)&p1;
    if (ok) *(uint2*)&xl2h[(size_t)arow * 32 + c0] = pv;
    ps += acc[ct][0] * as4.x + acc[ct][1] * as4.y +
          acc[ct][2] * as4.z + acc[ct][3] * as4.w;
    pd += acc[ct][0] * ad4.x + acc[ct][1] * ad4.y +
          acc[ct][2] * ad4.z + acc[ct][3] * ad4.w;
  }
  ps += __shfl_xor(ps, 16); ps += __shfl_xor(ps, 32);
  pd += __shfl_xor(pd, 16); pd += __shfl_xor(pd, 32);
  if (lg4 == 0 && ok) { ls2[arow] = ps; ld2[arow] = pd; }
}

// ---------------- Layer-2 gather + fused final FC ----------------------------
__global__ __launch_bounds__(256) void k_gather2_fc(
    const __half2* __restrict__ xl2h2, const float* __restrict__ ls2,
    const float* __restrict__ ld2, const int* __restrict__ cnt,
    const int* __restrict__ edge_src, const float* __restrict__ b2,
    const float* __restrict__ fcW, const float* __restrict__ fcb,
    float* __restrict__ out) {
  __shared__ float s2[16][33];
  const int t = threadIdx.x;
  const int g = t >> 4, q16 = t & 15;
  const int n = blockIdx.x * 16 + g;
  const float ldn = ld2[n];
  float lg = ls2[n] + ldn;                    // self loop
  lg = lg > 0.f ? lg : 0.2f * lg;
  const float w = __expf(lg);
  float ws0 = w, ws1 = 0.f;
  const float2 v0 = __half22float2(xl2h2[(size_t)n * 16 + q16]);
  float ax0 = w * v0.x, ay0 = w * v0.y, ax1 = 0.f, ay1 = 0.f;
  const int beg = n << 6;
  const int m = min(cnt[n], CAP);
  int i = 0;
  for (; i + 2 <= m; i += 2) {
    const int s0 = edge_src[beg + i];
    const int s1 = edge_src[beg + i + 1];
    float l0 = ls2[s0] + ldn;
    float l1 = ls2[s1] + ldn;
    l0 = l0 > 0.f ? l0 : 0.2f * l0;
    l1 = l1 > 0.f ? l1 : 0.2f * l1;
    const float w0 = __expf(l0), w1 = __expf(l1);
    const float2 f0 = __half22float2(xl2h2[(size_t)s0 * 16 + q16]);
    const float2 f1 = __half22float2(xl2h2[(size_t)s1 * 16 + q16]);
    ws0 += w0; ws1 += w1;
    ax0 += w0 * f0.x; ay0 += w0 * f0.y;
    ax1 += w1 * f1.x; ay1 += w1 * f1.y;
  }
  if (i < m) {
    const int s0 = edge_src[beg + i];
    float l0 = ls2[s0] + ldn;
    l0 = l0 > 0.f ? l0 : 0.2f * l0;
    const float w0 = __expf(l0);
    const float2 f0 = __half22float2(xl2h2[(size_t)s0 * 16 + q16]);
    ws0 += w0; ax0 += w0 * f0.x; ay0 += w0 * f0.y;
  }
  const float inv = 1.f / (ws0 + ws1);
  const float2 bb = *(const float2*)&b2[q16 * 2];
  s2[g][q16 * 2]     = fmaxf((ax0 + ax1) * inv + bb.x, 0.f);
  s2[g][q16 * 2 + 1] = fmaxf((ay0 + ay1) * inv + bb.y, 0.f);
  __syncthreads();
  const int rn = t >> 4;                      // node for FC epilogue
  const int jb = t & 15;
  const size_t obase = (size_t)(blockIdx.x * 16 + rn) * 128;
#pragma unroll
  for (int q = 0; q < 8; ++q) {
    const int j = jb + 16 * q;
    float o = fcb[j];
#pragma unroll
    for (int cc = 0; cc < 32; ++cc) o += s2[rn][cc] * fcW[(size_t)cc * 128 + j];
    out[obase + j] = o;
  }
}

extern "C" void kernel_launch(void* const* d_in, const int* in_sizes, int n_in,
                              void* d_out, int out_size, void* d_ws, size_t ws_size,
                              hipStream_t stream) {
  const float* x     = (const float*)d_in[0];
  const int*   ei    = (const int*)d_in[1];
  const float* W1    = (const float*)d_in[2];
  const float* asr1  = (const float*)d_in[3];
  const float* adt1  = (const float*)d_in[4];
  const float* b1    = (const float*)d_in[5];
  const float* W2    = (const float*)d_in[6];
  const float* asr2  = (const float*)d_in[7];
  const float* adt2  = (const float*)d_in[8];
  const float* b2    = (const float*)d_in[9];
  const float* fcW   = (const float*)d_in[10];
  const float* fcb   = (const float*)d_in[11];
  float* out = (float*)d_out;

  char* p = (char*)d_ws;
  size_t off = 0;
  auto alloc = [&](size_t bytes) {
    void* q = p + off;
    off = (off + bytes + 255) & ~(size_t)255;
    return q;
  };
  __half*  xl1h    = (__half*)alloc((size_t)NN * 256 * 2);
  __half*  h1h     = (__half*)alloc((size_t)NN * 256 * 2);
  float*   ls1     = (float*)alloc((size_t)NN * 4 * 4);
  float*   ld1     = (float*)alloc((size_t)NN * 4 * 4);
  __half*  xl2h    = (__half*)alloc((size_t)NN * 32 * 2);
  float*   ls2     = (float*)alloc((size_t)NN * 4);
  float*   ld2     = (float*)alloc((size_t)NN * 4);
  int*     cursor  = (int*)alloc((size_t)NN * 4);
  int*     edge_src= (int*)alloc((size_t)NN * CAP * 4);
  __half*  W1t     = (__half*)alloc((size_t)256 * 128 * 2);
  __half*  W2t     = (__half*)alloc((size_t)32 * 256 * 2);
  (void)ws_size; (void)n_in; (void)in_sizes; (void)out_size;

  hipMemsetAsync(cursor, 0, (size_t)NN * 4, stream);

  k_cvt<<<160, 256, 0, stream>>>(W1, W2, W1t, W2t);
  k_gemm1m<<<dim3(391, 2), 256, 0, stream>>>(x, W1t, asr1, adt1, xl1h, ls1, ld1);
  k_scatter<<<NE / 256, 256, 0, stream>>>(ei, cursor, edge_src);
  k_gather1<<<NN / 8, 256, 0, stream>>>((const uint4*)xl1h, ls1, ld1, cursor,
                                        edge_src, b1, (uint4*)h1h);
  k_gemm2m<<<(NN + 63) / 64, 256, 0, stream>>>(h1h, W2t, asr2, adt2, xl2h, ls2, ld2);
  k_gather2_fc<<<NN / 16, 256, 0, stream>>>((const __half2*)xl2h, ls2, ld2, cursor,
                                            edge_src, b2, fcW, fcb, out);
}